// Round 12
// baseline (112.030 us; speedup 1.0000x reference)
//
#include <hip/hip_runtime.h>

// Embeder: out[b,t,:] = W[x[b,t]] + (x[b,t] not end AND exists end at t'>t)
//                        ? 1.5*W[nearest-future-end-symbol] : 0
// Dtypes: weight f32 [256,512], x int32 [B,T], end_ids int32 [2], out f32 [B,T,D].

typedef float f4 __attribute__((ext_vector_type(4)));

constexpr int TT = 1024;     // T
constexpr int DD = 512;      // D
constexpr int C4 = DD / 4;   // 128 f4 chunks per D-row
constexpr int NW = TT / 64;  // 16 waves per block

__global__ __launch_bounds__(1024) void embeder_kernel(
    const float* __restrict__ weight,
    const int* __restrict__ x,
    const int* __restrict__ end_ids,
    float* __restrict__ out)
{
    __shared__ int wmin[NW];  // per-wave suffix-min totals
    __shared__ int code[TT];  // sym | (sel<<16); sel: 0=none, 1=e0, 2=e1

    const int b    = blockIdx.x;        // one block per row
    const int tid  = threadIdx.x;
    const int wid  = tid >> 6;
    const int lane = tid & 63;
    const int e0 = end_ids[0], e1 = end_ids[1];
    const int INF = 0x7FFFFFFF;

    // ---- hoisted: lane's end-row chunks at c4=lane and c4=lane+64, pre-scaled ----
    const f4* wv = (const f4*)weight;
    f4 ea_lo = wv[e0 * C4 + lane]      * 1.5f;
    f4 ea_hi = wv[e0 * C4 + 64 + lane] * 1.5f;
    f4 eb_lo = wv[e1 * C4 + lane]      * 1.5f;
    f4 eb_hi = wv[e1 * C4 + 64 + lane] * 1.5f;

    // ---- phase 1: nearest-future-end via shuffle-based suffix-min (2 barriers) ----
    int sym = x[b * TT + tid];
    bool is_end = (sym == e0) || (sym == e1);
    int v = is_end ? ((tid << 1) | (sym == e0 ? 0 : 1)) : INF;

    #pragma unroll
    for (int off = 1; off < 64; off <<= 1) {
        int u = __shfl_down(v, off);
        v = (lane + off < 64) ? min(v, u) : v;
    }
    if (lane == 0) wmin[wid] = v;   // whole-wave min
    __syncthreads();

    int tailMin = INF;
    for (int w = wid + 1; w < NW; ++w) tailMin = min(tailMin, wmin[w]);

    int nvWave = __shfl_down(v, 1);
    int nv = (lane < 63) ? min(nvWave, tailMin) : tailMin;

    int sel = 0;
    if (!is_end && nv != INF) sel = (nv & 1) + 1; // 1 -> +1.5*W[e0], 2 -> +1.5*W[e1]
    code[tid] = sym | (sel << 16);
    __syncthreads();

    // ---- phase 2: each wave owns a CONTIGUOUS 128 KB sub-slab, advances 1 KB/store ----
    f4* ov = (f4*)out + (size_t)b * TT * C4;
    const int wbase = wid * (TT * C4 / NW);   // wid * 8192 f4

    const int iters = (TT * C4) / 1024;       // 128 per thread
    #pragma unroll 8
    for (int k = 0; k < iters; ++k) {
        int idx = wbase + k * 64 + lane;      // sequential per wave
        int t   = wid * 64 + (k >> 1);        // wave-uniform token
        int c    = code[t];                   // LDS broadcast
        int symt = c & 0xFFFF;
        int selt = c >> 16;
        int hi   = k & 1;                     // which half of the D-row
        f4 wq = wv[symt * C4 + hi * 64 + lane];
        if (selt) {
            f4 e = hi ? ((selt == 1) ? ea_hi : eb_hi)
                      : ((selt == 1) ? ea_lo : eb_lo);
            wq += e;
        }
        __builtin_nontemporal_store(wq, &ov[idx]);
    }
}

extern "C" void kernel_launch(void* const* d_in, const int* in_sizes, int n_in,
                              void* d_out, int out_size, void* d_ws, size_t ws_size,
                              hipStream_t stream) {
    const float* weight  = (const float*)d_in[0];
    const int*   x       = (const int*)d_in[1];
    const int*   end_ids = (const int*)d_in[2];
    float*       out     = (float*)d_out;

    const int B = in_sizes[1] / TT;   // 256
    embeder_kernel<<<B, 1024, 0, stream>>>(weight, x, end_ids, out);
}

// Round 13
// 91.069 us; speedup vs baseline: 1.2302x; 1.2302x over previous
//
#include <hip/hip_runtime.h>

// Embeder: out[b,t,:] = W[x[b,t]] + (x[b,t] not end AND exists end at t'>t)
//                        ? 1.5*W[nearest-future-end-symbol] : 0
// Dtypes: weight f32 [256,512], x int32 [B,T], end_ids int32 [2], out f32 [B,T,D].
//
// Best config (R9): one 1024-thread block per row -> single 2 MB contiguous
// write stream per CU, block-wide advancing front; nt-stores; unroll 8;
// end-rows hoisted to registers pre-scaled; scan phase proven hidden (R3).

typedef float f4 __attribute__((ext_vector_type(4)));

constexpr int TT = 1024;     // T
constexpr int DD = 512;      // D
constexpr int C4 = DD / 4;   // 128 f4 chunks per D-row
constexpr int NW = TT / 64;  // 16 waves per block

__global__ __launch_bounds__(1024) void embeder_kernel(
    const float* __restrict__ weight,
    const int* __restrict__ x,
    const int* __restrict__ end_ids,
    float* __restrict__ out)
{
    __shared__ int wmin[NW];  // per-wave suffix-min totals
    __shared__ int code[TT];  // sym | (sel<<16); sel: 0=none, 1=e0, 2=e1

    const int b    = blockIdx.x;        // one block per row: 2 MB contiguous stream
    const int tid  = threadIdx.x;
    const int wid  = tid >> 6;
    const int lane = tid & 63;
    const int e0 = end_ids[0], e1 = end_ids[1];
    const int INF = 0x7FFFFFFF;

    // ---- hoisted: this lane's end-row chunks (loop-invariant), pre-scaled by 1.5 ----
    const int c4 = tid & 127;
    const f4* wv = (const f4*)weight;
    f4 ea = wv[e0 * C4 + c4] * 1.5f;
    f4 eb = wv[e1 * C4 + c4] * 1.5f;

    // ---- phase 1: nearest-future-end via shuffle-based suffix-min (2 barriers) ----
    int sym = x[b * TT + tid];
    bool is_end = (sym == e0) || (sym == e1);
    int v = is_end ? ((tid << 1) | (sym == e0 ? 0 : 1)) : INF;

    #pragma unroll
    for (int off = 1; off < 64; off <<= 1) {
        int u = __shfl_down(v, off);
        v = (lane + off < 64) ? min(v, u) : v;
    }
    if (lane == 0) wmin[wid] = v;   // whole-wave min
    __syncthreads();

    int tailMin = INF;
    for (int w = wid + 1; w < NW; ++w) tailMin = min(tailMin, wmin[w]);

    int nvWave = __shfl_down(v, 1);
    int nv = (lane < 63) ? min(nvWave, tailMin) : tailMin;

    int sel = 0;
    if (!is_end && nv != INF) sel = (nv & 1) + 1; // 1 -> +1.5*W[e0], 2 -> +1.5*W[e1]
    code[tid] = sym | (sel << 16);
    __syncthreads();

    // ---- phase 2: streaming write, 2 MB contiguous slab per block; nt-stores ----
    f4* ov = (f4*)out + (size_t)b * TT * C4;

    const int iters = (TT * C4) / 1024;   // 128
    #pragma unroll 8
    for (int k = 0; k < iters; ++k) {
        int idx = tid + k * 1024;
        int t   = idx >> 7;          // wave-uniform
        int c    = code[t];          // LDS broadcast within wave
        int symt = c & 0xFFFF;
        int selt = c >> 16;
        f4 wq = wv[symt * C4 + c4];
        if (selt) {
            f4 e = (selt == 1) ? ea : eb;   // wave-uniform select, registers only
            wq += e;
        }
        __builtin_nontemporal_store(wq, &ov[idx]);
    }
}

extern "C" void kernel_launch(void* const* d_in, const int* in_sizes, int n_in,
                              void* d_out, int out_size, void* d_ws, size_t ws_size,
                              hipStream_t stream) {
    const float* weight  = (const float*)d_in[0];
    const int*   x       = (const int*)d_in[1];
    const int*   end_ids = (const int*)d_in[2];
    float*       out     = (float*)d_out;

    const int B = in_sizes[1] / TT;   // 256
    embeder_kernel<<<B, 1024, 0, stream>>>(weight, x, end_ids, out);
}